// Round 11
// baseline (31.899 us; speedup 1.0000x reference)
//
#include <hip/hip_runtime.h>
#include <math.h>

// SCTC-SB loss, round 11: fwd+bwd fused into ONE 64-lane wave per (b,f).
// Lane l: fwd alphas f0..f3 (states 4l..4l+3, t=1..tm) and bwd betas b0..b3
// (t=Tin-2..tm+1) advance together each serial iteration -> two independent
// ~3-deep chains interleave in one wave's issue slots. No __syncthreads, no
// LDS exchange; gamma half-step in-wave; combine dot in fp64.
// Carries round-8/10 machinery: LDS-staged per-chunk softmax, register
// double-buffered groups of 8, deferred renorm, alpha-band mask + e<=2L
// combine mask (inf guard).

#define LOG2E 1.4426950408889634f
#define LN2d 0.69314718055994530942

constexpr int Bc = 16, Tc = 500, Sc = 100, Fc = 35;
constexpr int NPAIR = Bc * Fc;  // 560
constexpr int EXPB = 217;       // renorm target biased exponent (2^90)

__device__ __forceinline__ float dpp_shr1(float v) {  // lane l <- l-1, fill 0
  return __int_as_float(__builtin_amdgcn_update_dpp(
      0, __float_as_int(v), 0x138, 0xF, 0xF, false));
}
__device__ __forceinline__ float dpp_shl1(float v) {  // lane l <- l+1, fill 0
  return __int_as_float(__builtin_amdgcn_update_dpp(
      0, __float_as_int(v), 0x130, 0xF, 0xF, false));
}
template <int C>
__device__ __forceinline__ int dppmax(int v) {
  int t = __builtin_amdgcn_update_dpp(v, v, C, 0xF, 0xF, false);
  return max(v, t);
}

// 3-class softmax -> float4(q2, q0, q1-q0, 0); log2 domain
__device__ __forceinline__ float4 smf(float xr, float bl2) {
  const float x = xr * LOG2E;
  const float m = fmaxf(fabsf(x), bl2);
  const float u0 = exp2f(-x - m), u1 = exp2f(x - m), u2 = exp2f(bl2 - m);
  const float rz = 1.0f / (u0 + u1 + u2);
  return make_float4(u2 * rz, u0 * rz, (u1 - u0) * rz, 0.0f);
}

__global__ __launch_bounds__(64) void sctc_scan(
    const float* __restrict__ logits,       // (B,T,F)
    const float* __restrict__ blank_logit,  // (1,)
    const int* __restrict__ targets,        // (B,S,F) 0/1
    const int* __restrict__ in_len,         // (B,)
    const int* __restrict__ tgt_len,        // (B,)
    float* __restrict__ part) {             // (NPAIR,)
  __shared__ float4 stF[2][64];
  __shared__ float4 stB[2][64];
  const int lane = threadIdx.x;  // one wave per block
  const int p = blockIdx.x;
  const int b = p / Fc, f = p - b * Fc;
  const int Tin = in_len[b];  // uniform
  const int L = tgt_len[b];   // uniform
  const float bl2 = blank_logit[0] * LOG2E;
  const float* __restrict__ lg = logits + (size_t)b * Tc * Fc + f;
  const float S90 = __int_as_float((90 + 127) << 23);
  const int e0 = 4 * lane;

  const int tbase = b * Sc * Fc + f;
  const int t0 = targets[tbase + min(2 * lane, Sc - 1) * Fc];
  const int t1 = targets[tbase + min(2 * lane + 1, Sc - 1) * Fc];
  const int tprev = __shfl_up(t1, 1);     // tgt[2l-1]
  const int tnext0 = __shfl_down(t0, 1);  // tgt[2l+2]
  const float bt0f = t0 ? 1.0f : 0.0f, bt1f = t1 ? 1.0f : 0.0f;
  const float sk1f = (lane == 0 || t0 != tprev) ? 1.0f : 0.0f;
  const float sk3f = (t1 != t0) ? 1.0f : 0.0f;
  const float skBf = (tnext0 != t1) ? 1.0f : 0.0f;

  const int tm = (Tin - 1) >> 1;
  const int NF = tm;            // fwd steps: t = 1..tm
  const int NB = Tin - 2 - tm;  // bwd steps: t = Tin-2..tm+1 ; NF-NB in {0,1}

  const int e_hi = 2 * L + 1, twoLm1 = 2 * L - 1;
  const bool in0 = e0 <= e_hi, in1 = e0 + 1 <= e_hi, in2 = e0 + 2 <= e_hi,
             in3 = e0 + 3 <= e_hi;

  float f0 = 0.0f, f1 = 0.0f, f2 = 0.0f, f3 = 0.0f;
  float b0 = 0.0f, b1 = 0.0f, b2 = 0.0f, b3 = 0.0f;
  int offF = -90, offB = -90, mmF = 0, mmB = 0;

  {  // inits: fwd at t=0 (lane 0), bwd at t=Tin-1 (states 2L, 2L-1)
    const float4 c0 = smf(lg[0], bl2);
    if (lane == 0) {
      f0 = c0.x * S90;
      f1 = fmaf(bt0f, c0.z, c0.y) * S90;
    }
    const float4 cE = smf(lg[(Tin - 1) * Fc], bl2);
    if (e0 == 2 * L) b0 = cE.x * S90;
    if (e0 + 2 == 2 * L) b2 = cE.x * S90;
    if (e0 + 1 == twoLm1) b1 = fmaf(bt0f, cE.z, cE.y) * S90;
    if (e0 + 3 == twoLm1) b3 = fmaf(bt1f, cE.z, cE.y) * S90;
  }

  auto stepF = [&](const float4& G) {
    const float po0 = fmaf(bt0f, G.z, G.y);
    const float po1 = fmaf(bt1f, G.z, G.y);
    const float pr3 = dpp_shr1(f3);  // alpha[4l-1]
    const float s01 = f0 + f1, s12 = f1 + f2, s23 = f2 + f3;
    const float t0v = f0 + pr3;
    const float t1v = fmaf(pr3, sk1f, s01);
    const float t3v = fmaf(f1, sk3f, s23);
    f0 = t0v * G.x; f1 = t1v * po0; f2 = s12 * G.x; f3 = t3v * po1;
  };
  auto stepB = [&](const float4& G) {
    const float po0 = fmaf(bt0f, G.z, G.y);
    const float po1 = fmaf(bt1f, G.z, G.y);
    const float nb0 = dpp_shl1(b0);  // beta[4l+4]
    const float nb1 = dpp_shl1(b1);  // beta[4l+5]
    const float s01 = b0 + b1, s12 = b1 + b2, s23 = b2 + b3;
    const float t1v = fmaf(b3, sk3f, s12);
    const float t3v = fmaf(nb1, skBf, b3 + nb0);
    b0 = s01 * G.x; b1 = t1v * po0; b2 = s23 * G.x; b3 = t3v * po1;
  };
  auto snapF = [&](int il) {  // il = fwd step index just completed; t = 1+il
    const int t = 1 + il;
    const int elo = twoLm1 - 2 * (Tin - 1 - t);
    const int x0 = (in0 && e0 >= elo) ? (__float_as_int(f0) >> 23) : 0;
    const int x1 = (in1 && e0 + 1 >= elo) ? (__float_as_int(f1) >> 23) : 0;
    const int x2 = (in2 && e0 + 2 >= elo) ? (__float_as_int(f2) >> 23) : 0;
    const int x3 = (in3 && e0 + 3 >= elo) ? (__float_as_int(f3) >> 23) : 0;
    mmF = max(max(x0, x1), max(x2, x3));
  };
  auto snapB = [&]() {  // beta: states > 2L exactly 0; unmasked
    const int x0 = __float_as_int(b0) >> 23, x1 = __float_as_int(b1) >> 23;
    const int x2 = __float_as_int(b2) >> 23, x3 = __float_as_int(b3) >> 23;
    mmB = max(max(x0, x1), max(x2, x3));
  };
  auto treeF = [&]() {
    mmF = dppmax<0x111>(mmF); mmF = dppmax<0x112>(mmF);
    mmF = dppmax<0x114>(mmF); mmF = dppmax<0x118>(mmF);
    mmF = dppmax<0x142>(mmF); mmF = dppmax<0x143>(mmF);
  };
  auto treeB = [&]() {
    mmB = dppmax<0x111>(mmB); mmB = dppmax<0x112>(mmB);
    mmB = dppmax<0x114>(mmB); mmB = dppmax<0x118>(mmB);
    mmB = dppmax<0x142>(mmB); mmB = dppmax<0x143>(mmB);
  };
  auto applyF = [&]() {
    const int mw = __builtin_amdgcn_readlane(mmF, 63);
    int k = EXPB - mw;
    k = min(max(k, -126), 126);
    const float sc = __int_as_float((k + 127) << 23);
    f0 *= sc; f1 *= sc; f2 *= sc; f3 *= sc;
    offF -= k;
  };
  auto applyB = [&]() {
    const int mw = __builtin_amdgcn_readlane(mmB, 63);
    int k = EXPB - mw;
    k = min(max(k, -126), 126);
    const float sc = __int_as_float((k + 127) << 23);
    b0 *= sc; b1 *= sc; b2 *= sc; b3 *= sc;
    offB -= k;
  };

  // process 8 step-pairs from PFr/PBr, prefetch into QFr/QBr
  auto group2 = [&](float4 (&PFr)[8], float4 (&QFr)[8], const float4* sF,
                    float4 (&PBr)[8], float4 (&QBr)[8], const float4* sB,
                    int ilast) {
#pragma unroll
    for (int i = 0; i < 8; ++i) { QFr[i] = sF[i]; QBr[i] = sB[i]; }
    stepF(PFr[0]); stepB(PBr[0]); treeF();
    stepF(PFr[1]); stepB(PBr[1]); treeB();
    stepF(PFr[2]); stepB(PBr[2]); applyF();
    stepF(PFr[3]); stepB(PBr[3]); applyB();
    stepF(PFr[4]); stepB(PBr[4]);
    stepF(PFr[5]); stepB(PBr[5]);
    stepF(PFr[6]); stepB(PBr[6]);
    stepF(PFr[7]); stepB(PBr[7]);
    snapF(ilast); snapB();
  };

  // prologue: stage chunk0 both dirs; preload raw logits for chunk1
  float xF = lg[min(1 + lane, Tc - 1) * Fc];
  float xB = lg[max(Tin - 2 - lane, 0) * Fc];
  stF[0][lane] = smf(xF, bl2);
  stB[0][lane] = smf(xB, bl2);
  xF = lg[min(65 + lane, Tc - 1) * Fc];
  xB = lg[max(Tin - 66 - lane, 0) * Fc];

  float4 PF[8], QF[8], PB[8], QB[8];
#pragma unroll
  for (int i = 0; i < 8; ++i) { PF[i] = stF[0][i]; PB[i] = stB[0][i]; }
  snapF(-1);  // t=0: elo very negative -> all in-band
  snapB();

  int buf = 0, ib = 0;
  for (; ib + 64 <= NB; ib += 64) {
    if (ib + 64 < NB) {
      stF[buf ^ 1][lane] = smf(xF, bl2);
      stB[buf ^ 1][lane] = smf(xB, bl2);
      xF = lg[min(1 + ib + 128 + lane, Tc - 1) * Fc];
      xB = lg[max(Tin - 2 - ib - 128 - lane, 0) * Fc];
    }
    const float4* cF = &stF[buf][0];
    const float4* cB = &stB[buf][0];
    const float4* nF = &stF[buf ^ 1][0];
    const float4* nB = &stB[buf ^ 1][0];
#pragma unroll
    for (int d = 0; d < 4; ++d) {
      group2(PF, QF, cF + 8 * (2 * d + 1), PB, QB, cB + 8 * (2 * d + 1),
             ib + 16 * d + 7);
      group2(QF, PF, (d < 3) ? cF + 8 * (2 * d + 2) : nF, QB, PB,
             (d < 3) ? cB + 8 * (2 * d + 2) : nB, ib + 16 * d + 15);
    }
    buf ^= 1;
  }
  {  // tail: n in [0,63] shared step-pairs, immediate renorm per 8
    const int n = NB - ib;
    const float4* cF = &stF[buf][0];
    const float4* cB = &stB[buf][0];
#pragma unroll
    for (int grp = 0; grp < 8; ++grp) {
      if (8 * grp >= n) break;  // wave-uniform
      float4 gF[8], gB[8];
#pragma unroll
      for (int i = 0; i < 8; ++i) { gF[i] = cF[8 * grp + i]; gB[i] = cB[8 * grp + i]; }
#pragma unroll
      for (int i = 0; i < 8; ++i) {
        if (8 * grp + i >= n) break;  // wave-uniform
        stepF(gF[i]); stepB(gB[i]);
      }
      if (8 * grp + 8 <= n) {
        snapF(ib + 8 * grp + 7); treeF(); applyF();
        snapB(); treeB(); applyB();
      }
    }
  }
  if (NF > NB) {  // odd Tin: one extra fwd step at t = tm (direct softmax)
    const float4 g = smf(lg[tm * Fc], bl2);
    stepF(g);
  }

  // combine: gamma half-step on beta_{tm+1}, dot with alpha_tm in fp64
  const float nb0 = dpp_shl1(b0), nb1 = dpp_shl1(b1);
  const float g0 = b0 + b1;
  const float g1 = fmaf(b3, sk3f, b1 + b2);
  const float g2 = b2 + b3;
  const float g3 = fmaf(nb1, skBf, b3 + nb0);
  // mask alpha to e <= 2L: out-of-band alphas may be +inf (excluded from
  // renorm max by design); gamma there is exactly 0; inf*0 = NaN guard.
  const int twoL = 2 * L;
  const float z0 = (e0 <= twoL) ? f0 : 0.0f;
  const float z1 = (e0 + 1 <= twoL) ? f1 : 0.0f;
  const float z2 = (e0 + 2 <= twoL) ? f2 : 0.0f;
  const float z3 = (e0 + 3 <= twoL) ? f3 : 0.0f;
  double d = (double)z0 * g0 + (double)z1 * g1 + (double)z2 * g2 +
             (double)z3 * g3;
  for (int o = 32; o >= 1; o >>= 1) d += __shfl_down(d, o);
  if (lane == 0) {
    const int offT = offF + offB;
    float val = 0.0f;
    if (d > 0.0) {
      int ex;
      const double mant = frexp(d, &ex);
      const double ll2 = (double)(ex + offT) + log2(mant);
      double ld = -ll2 * LN2d;
      if (ld > 0.5e30) ld = 0.0;  // zero_infinity
      val = (float)(ld / (double)L) * (1.0f / (float)NPAIR);
    }
    part[p] = val;
  }
}

__global__ __launch_bounds__(256) void sctc_reduce(const float* __restrict__ ws,
                                                   float* __restrict__ out) {
  const int tid = threadIdx.x;
  float s = 0.0f;
  for (int i = tid; i < NPAIR; i += 256) s += ws[i];
  for (int o = 32; o >= 1; o >>= 1) s += __shfl_down(s, o);
  __shared__ float partial[4];
  if ((tid & 63) == 0) partial[tid >> 6] = s;
  __syncthreads();
  if (tid == 0) out[0] = partial[0] + partial[1] + partial[2] + partial[3];
}

extern "C" void kernel_launch(void* const* d_in, const int* in_sizes, int n_in,
                              void* d_out, int out_size, void* d_ws,
                              size_t ws_size, hipStream_t stream) {
  const float* logits = (const float*)d_in[0];
  const float* blank_logit = (const float*)d_in[1];
  const int* targets = (const int*)d_in[2];
  const int* in_len = (const int*)d_in[3];
  const int* tgt_len = (const int*)d_in[4];
  float* part = (float*)d_ws;
  float* out = (float*)d_out;

  sctc_scan<<<NPAIR, 64, 0, stream>>>(logits, blank_logit, targets, in_len,
                                      tgt_len, part);
  sctc_reduce<<<1, 256, 0, stream>>>(part, out);
}